// Round 15
// baseline (650.883 us; speedup 1.0000x reference)
//
#include <hip/hip_runtime.h>
#include <hip/hip_fp16.h>
#include <math.h>

#define NN 100000
#define NE 1600000
#define ET (NE + NN)      // edges + self loops
#define NG 512
#define STATS_BLOCKS 240
#define PSLOTS (ET + 7 * NN + 16)              // padded edge-slot capacity (+16: GRP=16 overrun)

// bucket sort params
#define BSH 9                      // 512 nodes per bucket
#define NB  ((NN + 511) / 512)     // 196 buckets
#define BCAP 12288                 // cap per bucket (mean ~8700)
#define CHUNK 4096

// ---------------- pass1: partition edges into coarse buckets ----------------

__global__ __launch_bounds__(256) void part_pass1(const int* __restrict__ ei,
                                                  int* __restrict__ bcur,
                                                  unsigned* __restrict__ pairs) {
    __shared__ unsigned pck[CHUNK];
    __shared__ unsigned ordv[CHUNK];
    __shared__ unsigned char bkt[CHUNK];
    __shared__ unsigned char obkt[CHUNK];
    __shared__ int hist[NB + 1];
    __shared__ int lofs[NB + 1];
    __shared__ int cur[NB + 1];
    __shared__ int gpos[NB];
    __shared__ int lh[256];

    int t = threadIdx.x;
    int base = blockIdx.x * CHUNK;
    for (int i = t; i <= NB; i += 256) hist[i] = 0;
    __syncthreads();
    for (int i = t; i < CHUNK; i += 256) {
        int e = base + i;
        int b;
        unsigned p = 0;
        if (e < ET) {
            int s, d;
            if (e < NE) { s = ei[e]; d = ei[NE + e]; }
            else        { s = d = e - NE; }
            b = d >> BSH;
            p = ((unsigned)s << BSH) | (unsigned)(d & 511);
        } else b = NB;
        bkt[i] = (unsigned char)b;
        pck[i] = p;
        atomicAdd(&hist[b], 1);
    }
    __syncthreads();
    int v = (t <= NB) ? hist[t] : 0;
    lh[t] = v;
    __syncthreads();
    for (int off = 1; off < 256; off <<= 1) {
        int x = (t >= off) ? lh[t - off] : 0;
        __syncthreads();
        lh[t] += x;
        __syncthreads();
    }
    if (t <= NB) { lofs[t] = lh[t] - v; cur[t] = lh[t] - v; }
    __syncthreads();
    if (t < NB) {
        int h = hist[t];
        gpos[t] = (h > 0) ? atomicAdd(&bcur[t], h) : 0;
    }
    __syncthreads();
    for (int i = t; i < CHUNK; i += 256) {
        int b = bkt[i];
        int pos = atomicAdd(&cur[b], 1);
        ordv[pos] = pck[i];
        obkt[pos] = (unsigned char)b;
    }
    __syncthreads();
    int nvalid = lofs[NB];
    for (int i = t; i < nvalid; i += 256) {
        int b = obkt[i];
        int dst = gpos[b] + (i - lofs[b]);
        if (dst < BCAP) pairs[(size_t)b * BCAP + dst] = ordv[i];
    }
}

// ---------------- pass2a: per-bucket node counts + padded bucket sums ----------------

__global__ __launch_bounds__(256) void bucket_counts(const unsigned* __restrict__ pairs,
                                                     const int* __restrict__ bcur,
                                                     int* __restrict__ counts,
                                                     int* __restrict__ bsum) {
    __shared__ int lhist[512];
    __shared__ int rs[256];
    int b = blockIdx.x;
    int t = threadIdx.x;
    for (int i = t; i < 512; i += 256) lhist[i] = 0;
    __syncthreads();
    int cnt = min(bcur[b], BCAP);
    const unsigned* seg = pairs + (size_t)b * BCAP;
    for (int i = t; i < cnt; i += 256)
        atomicAdd(&lhist[seg[i] & 511], 1);
    __syncthreads();
    int nbase = b << BSH;
    int ps = 0;
    for (int i = t; i < 512; i += 256) {
        int n = nbase + i;
        int h = lhist[i];
        if (n < NN) {
            counts[n] = h;
            ps += (h + 7) & ~7;
        }
    }
    rs[t] = ps;
    __syncthreads();
    for (int off = 128; off > 0; off >>= 1) {
        if (t < off) rs[t] += rs[t + off];
        __syncthreads();
    }
    if (t == 0) bsum[b] = rs[0];
}

// ---------------- scan over 196 bucket sums; writes total + zeroes overrun tail ----------------

__global__ void scan_buckets(const int* __restrict__ bsum, int* __restrict__ boff,
                             int* __restrict__ total_loc, int* __restrict__ srcs) {
    __shared__ int lds[256];
    int t = threadIdx.x;
    int v = (t < NB) ? bsum[t] : 0;
    lds[t] = v;
    __syncthreads();
    for (int off = 1; off < 256; off <<= 1) {
        int x = (t >= off) ? lds[t - off] : 0;
        __syncthreads();
        lds[t] += x;
        __syncthreads();
    }
    if (t < NB) boff[t] = lds[t] - v;
    int total = lds[255];
    if (t == NB - 1) { boff[NB] = total; *total_loc = total; }
    if (t < 16) srcs[total + t] = 0;   // GRP=16 score-lane overrun tail
}

// ---------------- per-bucket padded exclusive scan -> offsets ----------------

__global__ __launch_bounds__(512) void scan_final_bucket(const int* __restrict__ counts,
                                                         const int* __restrict__ boff,
                                                         int* __restrict__ offsets) {
    __shared__ int lds[512];
    int b = blockIdx.x, t = threadIdx.x;
    int n = (b << BSH) + t;
    int v = (n < NN) ? ((counts[n] + 7) & ~7) : 0;
    lds[t] = v;
    __syncthreads();
    for (int off = 1; off < 512; off <<= 1) {
        int x = (t >= off) ? lds[t - off] : 0;
        __syncthreads();
        lds[t] += x;
        __syncthreads();
    }
    if (n < NN) offsets[n] = boff[b] + lds[t] - v;
}

// ---------------- pass2b: per-bucket scatter + zero-fill pad slots ----------------

__global__ __launch_bounds__(256) void bucket_scatter(const unsigned* __restrict__ pairs,
                                                      const int* __restrict__ bcur,
                                                      const int* __restrict__ offsets,
                                                      int* __restrict__ srcs) {
    __shared__ int cur[512];
    int b = blockIdx.x;
    int t = threadIdx.x;
    int nbase = b << BSH;
    for (int i = t; i < 512; i += 256) {
        int n = nbase + i;
        cur[i] = (n < NN) ? offsets[n] : 0;
    }
    __syncthreads();
    int cnt = min(bcur[b], BCAP);
    const unsigned* seg = pairs + (size_t)b * BCAP;
    for (int i = t; i < cnt; i += 256) {
        unsigned p = seg[i];
        int pos = atomicAdd(&cur[p & 511], 1);
        srcs[pos] = (int)(p >> BSH);
    }
    __syncthreads();
    // zero-fill pad slots [offsets+deg, offsets+pad) — replaces the global memset
    for (int i = t; i < 512; i += 256) {
        int n = nbase + i;
        if (n < NN) {
            int o = offsets[n];
            int fin = cur[i];
            int padEnd = o + ((fin - o + 7) & ~7);
            for (int p = fin; p < padEnd; ++p) srcs[p] = 0;
        }
    }
}

// ---------------- graph boundaries via binary search (batch is sorted) ----------------

__global__ void graph_bounds(const int* __restrict__ batch, int* __restrict__ goff) {
    int g = blockIdx.x * blockDim.x + threadIdx.x;
    if (g > NG) return;
    int lo = 0, hi = NN;
    while (lo < hi) {
        int mid = (lo + hi) >> 1;
        if (batch[mid] < g) lo = mid + 1; else hi = mid;
    }
    goff[g] = lo;
}

// ---------------- gemm1: Hh = fp16( X @ W1 ), fused per-head scores ----------------

__global__ __launch_bounds__(256) void gemm1(const float* __restrict__ X,
                                             const float* __restrict__ W,
                                             const float* __restrict__ a_s,
                                             const float* __restrict__ a_d,
                                             __half* __restrict__ Hh,
                                             float* __restrict__ SS,
                                             float* __restrict__ SD) {
    __shared__ float wl[128 * 64];
    __shared__ float xl[32 * 132];
    int t = threadIdx.x;
    int n0 = blockIdx.x * 32;
    for (int i = t * 4; i < 128 * 64; i += 1024)
        *(float4*)&wl[i] = *(const float4*)&W[i];
    for (int i = t * 4; i < 32 * 128; i += 1024) {
        int r = i >> 7, c = i & 127;
        int n = n0 + r;
        float4 v = (n < NN) ? *(const float4*)&X[(size_t)n * 128 + c] : make_float4(0, 0, 0, 0);
        *(float4*)&xl[r * 132 + c] = v;
    }
    __syncthreads();
    int cg = (t & 15) * 4;
    int ng = (t >> 4) * 2;
    float acc[2][4] = {};
    for (int k = 0; k < 128; ++k) {
        float4 w4 = *(float4*)&wl[k * 64 + cg];
        #pragma unroll
        for (int j = 0; j < 2; ++j) {
            float xv = xl[(ng + j) * 132 + k];
            acc[j][0] += xv * w4.x; acc[j][1] += xv * w4.y;
            acc[j][2] += xv * w4.z; acc[j][3] += xv * w4.w;
        }
    }
    int hd = cg >> 3;          // head (C=8), channels cg..cg+3 are half of head hd
    int half = cg & 7;         // 0 or 4
    #pragma unroll
    for (int j = 0; j < 2; ++j) {
        int n = n0 + ng + j;
        float p1 = 0.f, p2 = 0.f;
        #pragma unroll
        for (int k = 0; k < 4; ++k) {
            p1 += acc[j][k] * a_s[hd * 8 + half + k];
            p2 += acc[j][k] * a_d[hd * 8 + half + k];
        }
        float f1 = p1 + __shfl_xor(p1, 1, 64);
        float f2 = p2 + __shfl_xor(p2, 1, 64);
        if (n < NN) {
            __half2 q0 = __floats2half2_rn(acc[j][0], acc[j][1]);
            __half2 q1 = __floats2half2_rn(acc[j][2], acc[j][3]);
            *(__half2*)&Hh[(size_t)n * 64 + cg] = q0;
            *(__half2*)&Hh[(size_t)n * 64 + cg + 2] = q1;
            if (half == 0) {
                SS[(unsigned)n * 8 + hd] = f1;
                SD[(unsigned)n * 8 + hd] = f2;
            }
        }
    }
}

// ---------------- GAT gather: lane-specialized scores + shfl broadcast ----------------

template <int HEADS, int C, int PL, int GRP>
__global__ __launch_bounds__(256) void gat_kernel(const __half* __restrict__ Hh,
                                                  const float* __restrict__ SS,
                                                  const float* __restrict__ SD,
                                                  const int* __restrict__ offsets,
                                                  const int* __restrict__ counts,
                                                  const int* __restrict__ srcs,
                                                  const float* __restrict__ bias,
                                                  __half* __restrict__ GO) {
    constexpr int CH = HEADS * C;  // 64 or 96
    constexpr int LG = (GRP == 16) ? 4 : 3;
    int wid = blockIdx.x * (blockDim.x >> 6) + (threadIdx.x >> 6);
    int lane = threadIdx.x & 63;
    if (wid >= NN) return;
    int ch0 = lane * PL;
    bool active = ch0 < CH;
    int ch0l = active ? ch0 : 0;
    int head = active ? (ch0 / C) : 0;
    int headGRP = head * GRP;          // consumer's score-lane base
    int beg = offsets[wid], end = offsets[wid + 1];
    int deg = counts[wid];
    int sEdge = lane & (GRP - 1);
    int sHead = (lane >> LG) & (HEADS - 1);
    float sdvS = SD[(unsigned)wid * HEADS + sHead];
    float s = 0.f, a0 = 0.f, a1 = 0.f;
    for (int e = beg; e < end; e += GRP) {
        // --- score phase: one per lane ---
        int myIdx = e + sEdge;
        int mySrc = srcs[myIdx];
        float sc = SS[(unsigned)mySrc * HEADS + sHead] + sdvS;
        sc = fmaxf(sc, 0.f) + 0.2f * fminf(sc, 0.f);
        float myW = (myIdx - beg) < deg ? __expf(sc) : 0.f;
        // --- broadcast to consumers ---
        int sv[GRP];
        float wv[GRP];
        #pragma unroll
        for (int i = 0; i < GRP; ++i) {
            sv[i] = __shfl(mySrc, headGRP + i, 64);
            wv[i] = __shfl(myW, headGRP + i, 64);
        }
        // --- gather H + accumulate ---
        if (PL == 1) {
            float hv[GRP];
            #pragma unroll
            for (int i = 0; i < GRP; ++i)
                hv[i] = __half2float(Hh[(unsigned)(sv[i] * CH) + ch0l]);
            float pw[GRP / 2], pa[GRP / 2];
            #pragma unroll
            for (int i = 0; i < GRP / 2; ++i) {
                pw[i] = wv[2 * i] + wv[2 * i + 1];
                pa[i] = wv[2 * i] * hv[2 * i] + wv[2 * i + 1] * hv[2 * i + 1];
            }
            #pragma unroll
            for (int st = GRP / 4; st >= 1; st >>= 1) {
                #pragma unroll
                for (int i = 0; i < st; ++i) { pw[i] += pw[i + st]; pa[i] += pa[i + st]; }
            }
            s += pw[0];
            a0 += pa[0];
        } else {
            float hv0[GRP], hv1[GRP];
            #pragma unroll
            for (int i = 0; i < GRP; ++i) {
                __half2 hp = *(const __half2*)&Hh[(unsigned)(sv[i] * CH) + ch0l];
                hv0[i] = __low2float(hp); hv1[i] = __high2float(hp);
            }
            float pw[GRP / 2], pa[GRP / 2], pb[GRP / 2];
            #pragma unroll
            for (int i = 0; i < GRP / 2; ++i) {
                pw[i] = wv[2 * i] + wv[2 * i + 1];
                pa[i] = wv[2 * i] * hv0[2 * i] + wv[2 * i + 1] * hv0[2 * i + 1];
                pb[i] = wv[2 * i] * hv1[2 * i] + wv[2 * i + 1] * hv1[2 * i + 1];
            }
            #pragma unroll
            for (int st = GRP / 4; st >= 1; st >>= 1) {
                #pragma unroll
                for (int i = 0; i < st; ++i) { pw[i] += pw[i + st]; pa[i] += pa[i + st]; pb[i] += pb[i + st]; }
            }
            s += pw[0];
            a0 += pa[0];
            a1 += pb[0];
        }
    }
    if (active) {
        float inv = 1.f / s;
        if (PL == 2) {
            *(__half2*)&GO[(unsigned)(wid * CH) + ch0] =
                __floats2half2_rn(a0 * inv + bias[ch0], a1 * inv + bias[ch0 + 1]);
        } else {
            GO[(unsigned)(wid * CH) + ch0] = __float2half(a0 * inv + bias[ch0]);
        }
    }
}

// ---------------- fused BN stats + finalize (f32), last-block pattern ----------------

__global__ void stats_fused(const float* __restrict__ X, int Nn, int C, float invN,
                            const float* __restrict__ g, const float* __restrict__ be,
                            float* __restrict__ partial, int* __restrict__ done,
                            float* __restrict__ scale, float* __restrict__ shift) {
    extern __shared__ float lds[];
    int t = threadIdx.x;
    int c = t % C;
    int grp = t / C;
    int G_ = blockDim.x / C;
    float s = 0.f, q = 0.f;
    for (int n = blockIdx.x * G_ + grp; n < Nn; n += gridDim.x * G_) {
        float v = X[(size_t)n * C + c];
        s += v; q += v * v;
    }
    lds[t] = s; lds[blockDim.x + t] = q;
    __syncthreads();
    for (int off = blockDim.x >> 1; off >= C; off >>= 1) {
        if (t < off) {
            lds[t] += lds[t + off];
            lds[blockDim.x + t] += lds[blockDim.x + t + off];
        }
        __syncthreads();
    }
    if (t < C) {
        partial[(size_t)blockIdx.x * 2 * C + t] = lds[t];
        partial[(size_t)blockIdx.x * 2 * C + C + t] = lds[blockDim.x + t];
    }
    __threadfence();
    __shared__ int isLast;
    __syncthreads();
    if (t == 0) isLast = (atomicAdd(done, 1) == (int)gridDim.x - 1);
    __syncthreads();
    if (!isLast) return;
    __threadfence();
    float fs = 0.f, fq = 0.f;
    for (int b = grp; b < (int)gridDim.x; b += G_) {
        fs += partial[(size_t)b * 2 * C + c];
        fq += partial[(size_t)b * 2 * C + C + c];
    }
    __syncthreads();
    lds[t] = fs; lds[blockDim.x + t] = fq;
    __syncthreads();
    for (int off = blockDim.x >> 1; off >= C; off >>= 1) {
        if (t < off) {
            lds[t] += lds[t + off];
            lds[blockDim.x + t] += lds[blockDim.x + t + off];
        }
        __syncthreads();
    }
    if (t < C) {
        float mean = lds[t] * invN;
        float var = fmaxf(lds[blockDim.x + t] * invN - mean * mean, 0.f);
        float rs = rsqrtf(var + 1e-5f);
        float sc = g[t] * rs;
        scale[t] = sc;
        shift[t] = be[t] - mean * sc;
    }
}

// ---------------- fused BN stats + finalize (fp16, half2-vectorized) ----------------

__global__ void stats_h_fused(const __half* __restrict__ X, int Nn, int C, float invN,
                              const float* __restrict__ g, const float* __restrict__ be,
                              float* __restrict__ partial, int* __restrict__ done,
                              float* __restrict__ scale, float* __restrict__ shift) {
    extern __shared__ float lds[];
    int t = threadIdx.x;
    int C2 = C >> 1;
    int cp = t % C2;
    int grp = t / C2;
    int G_ = blockDim.x / C2;
    float s0 = 0.f, q0 = 0.f, s1 = 0.f, q1 = 0.f;
    for (int n = blockIdx.x * G_ + grp; n < Nn; n += gridDim.x * G_) {
        float2 v = __half22float2(*(const __half2*)&X[(size_t)n * C + cp * 2]);
        s0 += v.x; q0 += v.x * v.x;
        s1 += v.y; q1 += v.y * v.y;
    }
    float* L0 = lds;
    float* L1 = lds + blockDim.x;
    float* L2 = lds + 2 * blockDim.x;
    float* L3 = lds + 3 * blockDim.x;
    L0[t] = s0; L1[t] = s1; L2[t] = q0; L3[t] = q1;
    __syncthreads();
    for (int off = blockDim.x >> 1; off >= C2; off >>= 1) {
        if (t < off) {
            L0[t] += L0[t + off];
            L1[t] += L1[t + off];
            L2[t] += L2[t + off];
            L3[t] += L3[t + off];
        }
        __syncthreads();
    }
    if (t < C2) {
        partial[(size_t)blockIdx.x * 2 * C + 2 * t]     = L0[t];
        partial[(size_t)blockIdx.x * 2 * C + 2 * t + 1] = L1[t];
        partial[(size_t)blockIdx.x * 2 * C + C + 2 * t]     = L2[t];
        partial[(size_t)blockIdx.x * 2 * C + C + 2 * t + 1] = L3[t];
    }
    __threadfence();
    __shared__ int isLast;
    __syncthreads();
    if (t == 0) isLast = (atomicAdd(done, 1) == (int)gridDim.x - 1);
    __syncthreads();
    if (!isLast) return;
    __threadfence();
    int c = t % C;
    int fg = t / C;
    int FG = blockDim.x / C;
    float fs = 0.f, fq = 0.f;
    for (int b = fg; b < (int)gridDim.x; b += FG) {
        fs += partial[(size_t)b * 2 * C + c];
        fq += partial[(size_t)b * 2 * C + C + c];
    }
    __syncthreads();
    lds[t] = fs; lds[blockDim.x + t] = fq;
    __syncthreads();
    for (int off = blockDim.x >> 1; off >= C; off >>= 1) {
        if (t < off) {
            lds[t] += lds[t + off];
            lds[blockDim.x + t] += lds[blockDim.x + t + off];
        }
        __syncthreads();
    }
    if (t < C) {
        float mean = lds[t] * invN;
        float var = fmaxf(lds[blockDim.x + t] * invN - mean * mean, 0.f);
        float rs = rsqrtf(var + 1e-5f);
        float sc = g[t] * rs;
        scale[t] = sc;
        shift[t] = be[t] - mean * sc;
    }
}

// ---------------- relu(bn(X[N,64] fp16)) @ Lw(64,KOUT) + lb -> U ----------------

template <int KOUT>
__global__ __launch_bounds__(256) void bnrelu_linear(const __half* __restrict__ X,
                                                     const float* __restrict__ scale,
                                                     const float* __restrict__ shift,
                                                     const float* __restrict__ Lw,
                                                     const float* __restrict__ lb,
                                                     float* __restrict__ U) {
    __shared__ float tl[64 * 65];
    int t = threadIdx.x;
    int n0 = blockIdx.x * 64;
    for (int i = t * 4; i < 64 * 64; i += 1024) {
        int r = i >> 6, cc = i & 63;
        int n = n0 + r;
        float vv[4] = {0.f, 0.f, 0.f, 0.f};
        if (n < NN) {
            float2 v0 = __half22float2(*(const __half2*)&X[(size_t)n * 64 + cc]);
            float2 v1 = __half22float2(*(const __half2*)&X[(size_t)n * 64 + cc + 2]);
            vv[0] = v0.x; vv[1] = v0.y; vv[2] = v1.x; vv[3] = v1.y;
        }
        #pragma unroll
        for (int j = 0; j < 4; ++j)
            tl[r * 65 + cc + j] = fmaxf(vv[j] * scale[cc + j] + shift[cc + j], 0.f);
    }
    __syncthreads();
    int nl = t & 63;
    int kg = (t >> 6) * (KOUT / 4);
    float acc[KOUT / 4] = {};
    for (int l = 0; l < 64; ++l) {
        float v = tl[nl * 65 + l];
        #pragma unroll
        for (int j = 0; j < KOUT / 4; ++j) acc[j] += v * Lw[l * KOUT + kg + j];
    }
    int n = n0 + nl;
    if (n < NN)
        #pragma unroll
        for (int j = 0; j < KOUT / 4; ++j)
            U[(size_t)n * KOUT + kg + j] = acc[j] + lb[kg + j];
}

// ---------------- relu(bn(U)) @ W -> Hh (fp16), fused per-head scores ----------------

template <int CIN, int COUT, int H, int C>
__global__ __launch_bounds__(256) void bnrelu_gemm(const float* __restrict__ U,
                                                   const float* __restrict__ scale,
                                                   const float* __restrict__ shift,
                                                   const float* __restrict__ W,
                                                   const float* __restrict__ a_s,
                                                   const float* __restrict__ a_d,
                                                   __half* __restrict__ Hh,
                                                   float* __restrict__ SS,
                                                   float* __restrict__ SD) {
    static_assert(COUT / 4 == C && H == 4, "thread-per-head mapping");
    int t = threadIdx.x;
    int nl = t >> 2;
    int q = t & 3;
    int n = blockIdx.x * 64 + nl;
    if (n >= NN) return;
    constexpr int CPT = COUT / 4;
    float v[CIN];
    #pragma unroll
    for (int c = 0; c < CIN; ++c)
        v[c] = fmaxf(U[(size_t)n * CIN + c] * scale[c] + shift[c], 0.f);
    float acc[CPT] = {};
    #pragma unroll
    for (int c = 0; c < CIN; ++c) {
        #pragma unroll
        for (int j = 0; j < CPT; ++j) acc[j] += v[c] * W[c * COUT + q * CPT + j];
    }
    float s1 = 0.f, s2 = 0.f;
    #pragma unroll
    for (int j = 0; j < CPT; ++j) {
        s1 += acc[j] * a_s[q * C + j];
        s2 += acc[j] * a_d[q * C + j];
    }
    SS[(unsigned)n * H + q] = s1;
    SD[(unsigned)n * H + q] = s2;
    #pragma unroll
    for (int j = 0; j < CPT; j += 2)
        *(__half2*)&Hh[(size_t)n * COUT + q * CPT + j] = __floats2half2_rn(acc[j], acc[j + 1]);
}

// ---------------- fused mean-pool + classification head: block per graph ----------------

__global__ __launch_bounds__(128) void pool_head(const __half* __restrict__ GO,
                                                 const float* __restrict__ scale,
                                                 const float* __restrict__ shift,
                                                 const int* __restrict__ goff,
                                                 const float* __restrict__ oW,
                                                 const float* __restrict__ ob,
                                                 float* __restrict__ out) {
    __shared__ float red[8][16][2];
    __shared__ float pl[96];
    int g = blockIdx.x;
    int lp = threadIdx.x & 15;
    int row = threadIdx.x >> 4;
    int beg = goff[g], end = goff[g + 1];
    for (int cg = 0; cg < 3; ++cg) {
        int ch = cg * 32 + lp * 2;
        float sc0 = scale[ch], sh0 = shift[ch];
        float sc1 = scale[ch + 1], sh1 = shift[ch + 1];
        float s0 = 0.f, s1 = 0.f;
        for (int n = beg + row; n < end; n += 8) {
            float2 v = __half22float2(*(const __half2*)&GO[(size_t)n * 96 + ch]);
            s0 += fmaxf(v.x * sc0 + sh0, 0.f);
            s1 += fmaxf(v.y * sc1 + sh1, 0.f);
        }
        red[row][lp][0] = s0;
        red[row][lp][1] = s1;
        __syncthreads();
        if (row == 0) {
            #pragma unroll
            for (int r = 1; r < 8; ++r) { s0 += red[r][lp][0]; s1 += red[r][lp][1]; }
            float cnt = fmaxf((float)(end - beg), 1.f);
            pl[ch] = s0 / cnt;
            pl[ch + 1] = s1 / cnt;
        }
        __syncthreads();
    }
    if (threadIdx.x < 10) {
        float s = ob[threadIdx.x];
        for (int c = 0; c < 96; ++c) s += pl[c] * oW[c * 10 + threadIdx.x];
        out[g * 10 + threadIdx.x] = s;
    }
}

// ---------------- launch ----------------

extern "C" void kernel_launch(void* const* d_in, const int* in_sizes, int n_in,
                              void* d_out, int out_size, void* d_ws, size_t ws_size,
                              hipStream_t stream) {
    const float* x   = (const float*)d_in[0];
    const int*   ei  = (const int*)d_in[1];
    const int*   bat = (const int*)d_in[2];
    const float *W1 = (const float*)d_in[3], *a1s = (const float*)d_in[4],
                *a1d = (const float*)d_in[5], *b1 = (const float*)d_in[6],
                *g1 = (const float*)d_in[7], *be1 = (const float*)d_in[8],
                *lW1 = (const float*)d_in[9], *lb1 = (const float*)d_in[10],
                *gl1 = (const float*)d_in[11], *bel1 = (const float*)d_in[12],
                *W2 = (const float*)d_in[13], *a2s = (const float*)d_in[14],
                *a2d = (const float*)d_in[15], *b2 = (const float*)d_in[16],
                *g2 = (const float*)d_in[17], *be2 = (const float*)d_in[18],
                *lW2 = (const float*)d_in[19], *lb2 = (const float*)d_in[20],
                *gl2 = (const float*)d_in[21], *bel2 = (const float*)d_in[22],
                *W3 = (const float*)d_in[23], *a3s = (const float*)d_in[24],
                *a3d = (const float*)d_in[25], *b3 = (const float*)d_in[26],
                *g3 = (const float*)d_in[27], *be3 = (const float*)d_in[28],
                *oW = (const float*)d_in[29], *ob = (const float*)d_in[30];
    float* out = (float*)d_out;

    // workspace layout
    int* iw      = (int*)d_ws;
    int* bcur    = iw;                   // NB   (memset with done)
    int* done    = bcur + NB;            // 8 counters (memset)
    int* counts  = done + 8;             // NN
    int* offsets = counts + NN;          // NN+1 (padded offsets)
    int* goff    = offsets + NN + 1;     // NG+1
    int* bsum    = goff + NG + 1;        // NB
    int* boff    = bsum + NB;            // NB+1
    int* srcs    = boff + NB + 1;        // PSLOTS (includes +16 overrun pad)
    float* fw      = (float*)(srcs + PSLOTS);
    __half* GOh    = (__half*)fw;                // NN*96 halves (region reserved NN*96 floats)
    float* Ub      = fw + (size_t)NN * 96;       // NN*16
    float* SSb     = Ub + (size_t)NN * 16;       // NN*8
    float* SDb     = SSb + (size_t)NN * 8;       // NN*8
    float* partial = SDb + (size_t)NN * 8;       // STATS_BLOCKS*192
    float* scaleA  = partial + STATS_BLOCKS * 192;
    float* shiftA  = scaleA + 96;
    float* scaleB  = shiftA + 96;
    float* shiftB  = scaleB + 16;
    __half* Hh     = (__half*)(shiftB + 16);          // NN*96 halves
    unsigned* pairs = (unsigned*)GOh;            // aliases GO region during preprocessing

    const float invN = 1.0f / (float)NN;

    // ---- edge bucket sort -> padded CSR (shared by all layers) ----
    hipMemsetAsync(bcur, 0, (NB + 8) * sizeof(int), stream);
    part_pass1<<<(ET + CHUNK - 1) / CHUNK, 256, 0, stream>>>(ei, bcur, pairs);
    graph_bounds<<<3, 256, 0, stream>>>(bat, goff);
    bucket_counts<<<NB, 256, 0, stream>>>(pairs, bcur, counts, bsum);
    scan_buckets<<<1, 256, 0, stream>>>(bsum, boff, &offsets[NN], srcs);
    scan_final_bucket<<<NB, 512, 0, stream>>>(counts, boff, offsets);
    bucket_scatter<<<NB, 256, 0, stream>>>(pairs, bcur, offsets, srcs);

    // ---- layer 1 ----
    gemm1<<<(NN + 31) / 32, 256, 0, stream>>>(x, W1, a1s, a1d, Hh, SSb, SDb);
    gat_kernel<8, 8, 1, 8><<<(NN + 3) / 4, 256, 0, stream>>>(Hh, SSb, SDb, offsets, counts, srcs, b1, GOh);
    stats_h_fused<<<STATS_BLOCKS, 256, 4 * 256 * sizeof(float), stream>>>(GOh, NN, 64, invN, g1, be1, partial, done + 0, scaleA, shiftA);
    bnrelu_linear<8><<<(NN + 63) / 64, 256, 0, stream>>>(GOh, scaleA, shiftA, lW1, lb1, Ub);
    stats_fused<<<STATS_BLOCKS, 256, 4 * 256 * sizeof(float), stream>>>(Ub, NN, 8, invN, gl1, bel1, partial, done + 1, scaleB, shiftB);

    // ---- layer 2 ----
    bnrelu_gemm<8, 64, 4, 16><<<(NN + 63) / 64, 256, 0, stream>>>(Ub, scaleB, shiftB, W2, a2s, a2d, Hh, SSb, SDb);
    gat_kernel<4, 16, 1, 16><<<(NN + 3) / 4, 256, 0, stream>>>(Hh, SSb, SDb, offsets, counts, srcs, b2, GOh);
    stats_h_fused<<<STATS_BLOCKS, 256, 4 * 256 * sizeof(float), stream>>>(GOh, NN, 64, invN, g2, be2, partial, done + 2, scaleA, shiftA);
    bnrelu_linear<16><<<(NN + 63) / 64, 256, 0, stream>>>(GOh, scaleA, shiftA, lW2, lb2, Ub);
    stats_fused<<<STATS_BLOCKS, 256, 4 * 256 * sizeof(float), stream>>>(Ub, NN, 16, invN, gl2, bel2, partial, done + 3, scaleB, shiftB);

    // ---- layer 3 ----
    bnrelu_gemm<16, 96, 4, 24><<<(NN + 63) / 64, 256, 0, stream>>>(Ub, scaleB, shiftB, W3, a3s, a3d, Hh, SSb, SDb);
    gat_kernel<4, 24, 2, 8><<<(NN + 3) / 4, 256, 0, stream>>>(Hh, SSb, SDb, offsets, counts, srcs, b3, GOh);
    stats_h_fused<<<STATS_BLOCKS, 192, 4 * 192 * sizeof(float), stream>>>(GOh, NN, 96, invN, g3, be3, partial, done + 4, scaleA, shiftA);

    // ---- pool + head ----
    pool_head<<<NG, 128, 0, stream>>>(GOh, scaleA, shiftA, goff, oW, ob, out);
}

// Round 16
// 558.820 us; speedup vs baseline: 1.1647x; 1.1647x over previous
//
#include <hip/hip_runtime.h>
#include <hip/hip_fp16.h>
#include <math.h>

#define NN 100000
#define NE 1600000
#define ET (NE + NN)      // edges + self loops
#define NG 512
#define STATS_BLOCKS 240
#define SCAN_B 1024
#define SCAN_NB ((NN + SCAN_B - 1) / SCAN_B)   // 98
#define PSLOTS (ET + 7 * NN + 16)              // padded edge-slot capacity (+16: GRP=16 overrun)

// bucket sort params
#define BSH 9                      // 512 nodes per bucket
#define NB  ((NN + 511) / 512)     // 196 buckets
#define BCAP 12288                 // cap per bucket (mean ~8700)
#define CHUNK 4096

// ---------------- pass1: partition edges into coarse buckets ----------------

__global__ __launch_bounds__(256) void part_pass1(const int* __restrict__ ei,
                                                  int* __restrict__ bcur,
                                                  unsigned* __restrict__ pairs) {
    __shared__ unsigned pck[CHUNK];
    __shared__ unsigned ordv[CHUNK];
    __shared__ unsigned char bkt[CHUNK];
    __shared__ unsigned char obkt[CHUNK];
    __shared__ int hist[NB + 1];
    __shared__ int lofs[NB + 1];
    __shared__ int cur[NB + 1];
    __shared__ int gpos[NB];
    __shared__ int lh[256];

    int t = threadIdx.x;
    int base = blockIdx.x * CHUNK;
    for (int i = t; i <= NB; i += 256) hist[i] = 0;
    __syncthreads();
    for (int i = t; i < CHUNK; i += 256) {
        int e = base + i;
        int b;
        unsigned p = 0;
        if (e < ET) {
            int s, d;
            if (e < NE) { s = ei[e]; d = ei[NE + e]; }
            else        { s = d = e - NE; }
            b = d >> BSH;
            p = ((unsigned)s << BSH) | (unsigned)(d & 511);
        } else b = NB;
        bkt[i] = (unsigned char)b;
        pck[i] = p;
        atomicAdd(&hist[b], 1);
    }
    __syncthreads();
    int v = (t <= NB) ? hist[t] : 0;
    lh[t] = v;
    __syncthreads();
    for (int off = 1; off < 256; off <<= 1) {
        int x = (t >= off) ? lh[t - off] : 0;
        __syncthreads();
        lh[t] += x;
        __syncthreads();
    }
    if (t <= NB) { lofs[t] = lh[t] - v; cur[t] = lh[t] - v; }
    __syncthreads();
    if (t < NB) {
        int h = hist[t];
        gpos[t] = (h > 0) ? atomicAdd(&bcur[t], h) : 0;
    }
    __syncthreads();
    for (int i = t; i < CHUNK; i += 256) {
        int b = bkt[i];
        int pos = atomicAdd(&cur[b], 1);
        ordv[pos] = pck[i];
        obkt[pos] = (unsigned char)b;
    }
    __syncthreads();
    int nvalid = lofs[NB];
    for (int i = t; i < nvalid; i += 256) {
        int b = obkt[i];
        int dst = gpos[b] + (i - lofs[b]);
        if (dst < BCAP) pairs[(size_t)b * BCAP + dst] = ordv[i];
    }
}

// ---------------- pass2a: per-bucket node counts ----------------

__global__ __launch_bounds__(256) void bucket_counts(const unsigned* __restrict__ pairs,
                                                     const int* __restrict__ bcur,
                                                     int* __restrict__ counts) {
    __shared__ int lhist[512];
    int b = blockIdx.x;
    int t = threadIdx.x;
    for (int i = t; i < 512; i += 256) lhist[i] = 0;
    __syncthreads();
    int cnt = min(bcur[b], BCAP);
    const unsigned* seg = pairs + (size_t)b * BCAP;
    for (int i = t; i < cnt; i += 256)
        atomicAdd(&lhist[seg[i] & 511], 1);
    __syncthreads();
    int nbase = b << BSH;
    for (int i = t; i < 512; i += 256) {
        int n = nbase + i;
        if (n < NN) counts[n] = lhist[i];
    }
}

// ---------------- pass2b: per-bucket scatter into padded srcs ----------------

__global__ __launch_bounds__(256) void bucket_scatter(const unsigned* __restrict__ pairs,
                                                      const int* __restrict__ bcur,
                                                      const int* __restrict__ offsets,
                                                      int* __restrict__ srcs) {
    __shared__ int cur[512];
    int b = blockIdx.x;
    int t = threadIdx.x;
    int nbase = b << BSH;
    for (int i = t; i < 512; i += 256) {
        int n = nbase + i;
        cur[i] = (n < NN) ? offsets[n] : 0;
    }
    __syncthreads();
    int cnt = min(bcur[b], BCAP);
    const unsigned* seg = pairs + (size_t)b * BCAP;
    for (int i = t; i < cnt; i += 256) {
        unsigned p = seg[i];
        int pos = atomicAdd(&cur[p & 511], 1);
        srcs[pos] = (int)(p >> BSH);
    }
}

// ---------------- graph boundaries via binary search (batch is sorted) ----------------

__global__ void graph_bounds(const int* __restrict__ batch, int* __restrict__ goff) {
    int g = blockIdx.x * blockDim.x + threadIdx.x;
    if (g > NG) return;
    int lo = 0, hi = NN;
    while (lo < hi) {
        int mid = (lo + hi) >> 1;
        if (batch[mid] < g) lo = mid + 1; else hi = mid;
    }
    goff[g] = lo;
}

// ---------------- scans (counts rounded up to x8 inline -> padded offsets) ----------------

__global__ void scan_reduce(const int* __restrict__ in, int* __restrict__ bsum) {
    __shared__ int lds[256];
    int b = blockIdx.x, t = threadIdx.x;
    int s = 0;
    for (int i = t; i < SCAN_B; i += 256) {
        int idx = b * SCAN_B + i;
        if (idx < NN) s += (in[idx] + 7) & ~7;
    }
    lds[t] = s;
    __syncthreads();
    for (int off = 128; off > 0; off >>= 1) {
        if (t < off) lds[t] += lds[t + off];
        __syncthreads();
    }
    if (t == 0) bsum[b] = lds[0];
}

__global__ void scan_bsums(const int* __restrict__ bsum, int nb, int* __restrict__ boff,
                           int* __restrict__ total_loc) {
    __shared__ int lds[128];
    int t = threadIdx.x;
    int v = (t < nb) ? bsum[t] : 0;
    lds[t] = v;
    __syncthreads();
    for (int off = 1; off < 128; off <<= 1) {
        int x = (t >= off) ? lds[t - off] : 0;
        __syncthreads();
        lds[t] += x;
        __syncthreads();
    }
    if (t < nb) boff[t] = lds[t] - v;
    if (t == nb - 1) {
        boff[nb] = lds[t];
        if (total_loc) *total_loc = lds[t];
    }
}

__global__ void scan_final(const int* __restrict__ in, const int* __restrict__ boff,
                           int* __restrict__ out) {
    __shared__ int lds[SCAN_B];
    int b = blockIdx.x, t = threadIdx.x;
    int idx = b * SCAN_B + t;
    int v = (idx < NN) ? ((in[idx] + 7) & ~7) : 0;
    lds[t] = v;
    __syncthreads();
    for (int off = 1; off < SCAN_B; off <<= 1) {
        int x = (t >= off) ? lds[t - off] : 0;
        __syncthreads();
        lds[t] += x;
        __syncthreads();
    }
    if (idx < NN) out[idx] = boff[b] + lds[t] - v;
}

// ---------------- gemm1: Hh = fp16( X @ W1 ), fused per-head scores ----------------

__global__ __launch_bounds__(256) void gemm1(const float* __restrict__ X,
                                             const float* __restrict__ W,
                                             const float* __restrict__ a_s,
                                             const float* __restrict__ a_d,
                                             __half* __restrict__ Hh,
                                             float* __restrict__ SS,
                                             float* __restrict__ SD) {
    __shared__ float wl[128 * 64];
    __shared__ float xl[32 * 132];
    int t = threadIdx.x;
    int n0 = blockIdx.x * 32;
    for (int i = t * 4; i < 128 * 64; i += 1024)
        *(float4*)&wl[i] = *(const float4*)&W[i];
    for (int i = t * 4; i < 32 * 128; i += 1024) {
        int r = i >> 7, c = i & 127;
        int n = n0 + r;
        float4 v = (n < NN) ? *(const float4*)&X[(size_t)n * 128 + c] : make_float4(0, 0, 0, 0);
        *(float4*)&xl[r * 132 + c] = v;
    }
    __syncthreads();
    int cg = (t & 15) * 4;
    int ng = (t >> 4) * 2;
    float acc[2][4] = {};
    for (int k = 0; k < 128; ++k) {
        float4 w4 = *(float4*)&wl[k * 64 + cg];
        #pragma unroll
        for (int j = 0; j < 2; ++j) {
            float xv = xl[(ng + j) * 132 + k];
            acc[j][0] += xv * w4.x; acc[j][1] += xv * w4.y;
            acc[j][2] += xv * w4.z; acc[j][3] += xv * w4.w;
        }
    }
    int hd = cg >> 3;          // head (C=8), channels cg..cg+3 are half of head hd
    int half = cg & 7;         // 0 or 4
    #pragma unroll
    for (int j = 0; j < 2; ++j) {
        int n = n0 + ng + j;
        float p1 = 0.f, p2 = 0.f;
        #pragma unroll
        for (int k = 0; k < 4; ++k) {
            p1 += acc[j][k] * a_s[hd * 8 + half + k];
            p2 += acc[j][k] * a_d[hd * 8 + half + k];
        }
        float f1 = p1 + __shfl_xor(p1, 1, 64);
        float f2 = p2 + __shfl_xor(p2, 1, 64);
        if (n < NN) {
            __half2 q0 = __floats2half2_rn(acc[j][0], acc[j][1]);
            __half2 q1 = __floats2half2_rn(acc[j][2], acc[j][3]);
            *(__half2*)&Hh[(size_t)n * 64 + cg] = q0;
            *(__half2*)&Hh[(size_t)n * 64 + cg + 2] = q1;
            if (half == 0) {
                SS[(unsigned)n * 8 + hd] = f1;
                SD[(unsigned)n * 8 + hd] = f2;
            }
        }
    }
}

// ---------------- GAT gather: lane-specialized scores + shfl broadcast (R12 structure) ----------------

template <int HEADS, int C, int PL, int GRP>
__global__ __launch_bounds__(256) void gat_kernel(const __half* __restrict__ Hh,
                                                  const float* __restrict__ SS,
                                                  const float* __restrict__ SD,
                                                  const int* __restrict__ offsets,
                                                  const int* __restrict__ counts,
                                                  const int* __restrict__ srcs,
                                                  const float* __restrict__ bias,
                                                  __half* __restrict__ GO) {
    constexpr int CH = HEADS * C;  // 64 or 96
    constexpr int LG = (GRP == 16) ? 4 : 3;
    int wid = blockIdx.x * (blockDim.x >> 6) + (threadIdx.x >> 6);
    int lane = threadIdx.x & 63;
    if (wid >= NN) return;
    int ch0 = lane * PL;
    bool active = ch0 < CH;
    int ch0l = active ? ch0 : 0;
    int head = active ? (ch0 / C) : 0;
    int headGRP = head * GRP;          // consumer's score-lane base
    int beg = offsets[wid], end = offsets[wid + 1];
    int deg = counts[wid];
    int sEdge = lane & (GRP - 1);
    int sHead = (lane >> LG) & (HEADS - 1);
    float sdvS = SD[(unsigned)wid * HEADS + sHead];
    float s = 0.f, a0 = 0.f, a1 = 0.f;
    for (int e = beg; e < end; e += GRP) {
        // --- score phase: one per lane ---
        int myIdx = e + sEdge;
        int mySrc = srcs[myIdx];
        float sc = SS[(unsigned)mySrc * HEADS + sHead] + sdvS;
        sc = fmaxf(sc, 0.f) + 0.2f * fminf(sc, 0.f);
        float myW = (myIdx - beg) < deg ? __expf(sc) : 0.f;
        // --- broadcast to consumers ---
        int sv[GRP];
        float wv[GRP];
        #pragma unroll
        for (int i = 0; i < GRP; ++i) {
            sv[i] = __shfl(mySrc, headGRP + i, 64);
            wv[i] = __shfl(myW, headGRP + i, 64);
        }
        // --- gather H + accumulate ---
        if (PL == 1) {
            float hv[GRP];
            #pragma unroll
            for (int i = 0; i < GRP; ++i)
                hv[i] = __half2float(Hh[(unsigned)(sv[i] * CH) + ch0l]);
            float pw[GRP / 2], pa[GRP / 2];
            #pragma unroll
            for (int i = 0; i < GRP / 2; ++i) {
                pw[i] = wv[2 * i] + wv[2 * i + 1];
                pa[i] = wv[2 * i] * hv[2 * i] + wv[2 * i + 1] * hv[2 * i + 1];
            }
            #pragma unroll
            for (int st = GRP / 4; st >= 1; st >>= 1) {
                #pragma unroll
                for (int i = 0; i < st; ++i) { pw[i] += pw[i + st]; pa[i] += pa[i + st]; }
            }
            s += pw[0];
            a0 += pa[0];
        } else {
            float hv0[GRP], hv1[GRP];
            #pragma unroll
            for (int i = 0; i < GRP; ++i) {
                __half2 hp = *(const __half2*)&Hh[(unsigned)(sv[i] * CH) + ch0l];
                hv0[i] = __low2float(hp); hv1[i] = __high2float(hp);
            }
            float pw[GRP / 2], pa[GRP / 2], pb[GRP / 2];
            #pragma unroll
            for (int i = 0; i < GRP / 2; ++i) {
                pw[i] = wv[2 * i] + wv[2 * i + 1];
                pa[i] = wv[2 * i] * hv0[2 * i] + wv[2 * i + 1] * hv0[2 * i + 1];
                pb[i] = wv[2 * i] * hv1[2 * i] + wv[2 * i + 1] * hv1[2 * i + 1];
            }
            #pragma unroll
            for (int st = GRP / 4; st >= 1; st >>= 1) {
                #pragma unroll
                for (int i = 0; i < st; ++i) { pw[i] += pw[i + st]; pa[i] += pa[i + st]; pb[i] += pb[i + st]; }
            }
            s += pw[0];
            a0 += pa[0];
            a1 += pb[0];
        }
    }
    if (active) {
        float inv = 1.f / s;
        if (PL == 2) {
            *(__half2*)&GO[(unsigned)(wid * CH) + ch0] =
                __floats2half2_rn(a0 * inv + bias[ch0], a1 * inv + bias[ch0 + 1]);
        } else {
            GO[(unsigned)(wid * CH) + ch0] = __float2half(a0 * inv + bias[ch0]);
        }
    }
}

// ---------------- BN stats (deterministic two-stage) ----------------

__global__ void stats_kernel(const float* __restrict__ X, int Nn, int C,
                             float* __restrict__ partial) {
    int t = threadIdx.x;
    int c = t % C;
    int grp = t / C;
    int G_ = blockDim.x / C;
    float s = 0.f, q = 0.f;
    for (int n = blockIdx.x * G_ + grp; n < Nn; n += gridDim.x * G_) {
        float v = X[(size_t)n * C + c];
        s += v; q += v * v;
    }
    extern __shared__ float lds[];
    lds[t] = s; lds[blockDim.x + t] = q;
    __syncthreads();
    for (int off = blockDim.x >> 1; off >= C; off >>= 1) {
        if (t < off) {
            lds[t] += lds[t + off];
            lds[blockDim.x + t] += lds[blockDim.x + t + off];
        }
        __syncthreads();
    }
    if (t < C) {
        partial[(size_t)blockIdx.x * 2 * C + t] = lds[t];
        partial[(size_t)blockIdx.x * 2 * C + C + t] = lds[blockDim.x + t];
    }
}

// fp16 stats, half2-vectorized: thread owns channel pair c2=(t%(C/2))*2
__global__ void stats_h_kernel(const __half* __restrict__ X, int Nn, int C,
                               float* __restrict__ partial) {
    int t = threadIdx.x;
    int C2 = C >> 1;
    int cp = t % C2;
    int grp = t / C2;
    int G_ = blockDim.x / C2;
    float s0 = 0.f, q0 = 0.f, s1 = 0.f, q1 = 0.f;
    for (int n = blockIdx.x * G_ + grp; n < Nn; n += gridDim.x * G_) {
        float2 v = __half22float2(*(const __half2*)&X[(size_t)n * C + cp * 2]);
        s0 += v.x; q0 += v.x * v.x;
        s1 += v.y; q1 += v.y * v.y;
    }
    extern __shared__ float lds[];
    float* L0 = lds;
    float* L1 = lds + blockDim.x;
    float* L2 = lds + 2 * blockDim.x;
    float* L3 = lds + 3 * blockDim.x;
    L0[t] = s0; L1[t] = s1; L2[t] = q0; L3[t] = q1;
    __syncthreads();
    for (int off = blockDim.x >> 1; off >= C2; off >>= 1) {
        if (t < off) {
            L0[t] += L0[t + off];
            L1[t] += L1[t + off];
            L2[t] += L2[t + off];
            L3[t] += L3[t + off];
        }
        __syncthreads();
    }
    if (t < C2) {
        partial[(size_t)blockIdx.x * 2 * C + 2 * t]     = L0[t];
        partial[(size_t)blockIdx.x * 2 * C + 2 * t + 1] = L1[t];
        partial[(size_t)blockIdx.x * 2 * C + C + 2 * t]     = L2[t];
        partial[(size_t)blockIdx.x * 2 * C + C + 2 * t + 1] = L3[t];
    }
}

// parallel finalize: blockDim = C * G (G pow2), LDS tree reduce
__global__ void bn_finalize(const float* __restrict__ partial, int nb, int C, float invN,
                            const float* __restrict__ g, const float* __restrict__ be,
                            float* __restrict__ scale, float* __restrict__ shift) {
    extern __shared__ float red[];
    int t = threadIdx.x;
    int c = t % C;
    int grp = t / C;
    int G_ = blockDim.x / C;
    float s = 0.f, q = 0.f;
    for (int b = grp; b < nb; b += G_) {
        s += partial[(size_t)b * 2 * C + c];
        q += partial[(size_t)b * 2 * C + C + c];
    }
    red[t] = s; red[blockDim.x + t] = q;
    __syncthreads();
    for (int off = blockDim.x >> 1; off >= C; off >>= 1) {
        if (t < off) {
            red[t] += red[t + off];
            red[blockDim.x + t] += red[blockDim.x + t + off];
        }
        __syncthreads();
    }
    if (t < C) {
        float mean = red[t] * invN;
        float var = fmaxf(red[blockDim.x + t] * invN - mean * mean, 0.f);
        float rs = rsqrtf(var + 1e-5f);
        float sc = g[t] * rs;
        scale[t] = sc;
        shift[t] = be[t] - mean * sc;
    }
}

// ---------------- relu(bn(X[N,64] fp16)) @ Lw(64,KOUT) + lb -> U ----------------

template <int KOUT>
__global__ __launch_bounds__(256) void bnrelu_linear(const __half* __restrict__ X,
                                                     const float* __restrict__ scale,
                                                     const float* __restrict__ shift,
                                                     const float* __restrict__ Lw,
                                                     const float* __restrict__ lb,
                                                     float* __restrict__ U) {
    __shared__ float tl[64 * 65];
    int t = threadIdx.x;
    int n0 = blockIdx.x * 64;
    for (int i = t * 4; i < 64 * 64; i += 1024) {
        int r = i >> 6, cc = i & 63;
        int n = n0 + r;
        float vv[4] = {0.f, 0.f, 0.f, 0.f};
        if (n < NN) {
            float2 v0 = __half22float2(*(const __half2*)&X[(size_t)n * 64 + cc]);
            float2 v1 = __half22float2(*(const __half2*)&X[(size_t)n * 64 + cc + 2]);
            vv[0] = v0.x; vv[1] = v0.y; vv[2] = v1.x; vv[3] = v1.y;
        }
        #pragma unroll
        for (int j = 0; j < 4; ++j)
            tl[r * 65 + cc + j] = fmaxf(vv[j] * scale[cc + j] + shift[cc + j], 0.f);
    }
    __syncthreads();
    int nl = t & 63;
    int kg = (t >> 6) * (KOUT / 4);
    float acc[KOUT / 4] = {};
    for (int l = 0; l < 64; ++l) {
        float v = tl[nl * 65 + l];
        #pragma unroll
        for (int j = 0; j < KOUT / 4; ++j) acc[j] += v * Lw[l * KOUT + kg + j];
    }
    int n = n0 + nl;
    if (n < NN)
        #pragma unroll
        for (int j = 0; j < KOUT / 4; ++j)
            U[(size_t)n * KOUT + kg + j] = acc[j] + lb[kg + j];
}

// ---------------- relu(bn(U)) @ W -> Hh (fp16), fused per-head scores ----------------

template <int CIN, int COUT, int H, int C>
__global__ __launch_bounds__(256) void bnrelu_gemm(const float* __restrict__ U,
                                                   const float* __restrict__ scale,
                                                   const float* __restrict__ shift,
                                                   const float* __restrict__ W,
                                                   const float* __restrict__ a_s,
                                                   const float* __restrict__ a_d,
                                                   __half* __restrict__ Hh,
                                                   float* __restrict__ SS,
                                                   float* __restrict__ SD) {
    static_assert(COUT / 4 == C && H == 4, "thread-per-head mapping");
    int t = threadIdx.x;
    int nl = t >> 2;
    int q = t & 3;
    int n = blockIdx.x * 64 + nl;
    if (n >= NN) return;
    constexpr int CPT = COUT / 4;
    float v[CIN];
    #pragma unroll
    for (int c = 0; c < CIN; ++c)
        v[c] = fmaxf(U[(size_t)n * CIN + c] * scale[c] + shift[c], 0.f);
    float acc[CPT] = {};
    #pragma unroll
    for (int c = 0; c < CIN; ++c) {
        #pragma unroll
        for (int j = 0; j < CPT; ++j) acc[j] += v[c] * W[c * COUT + q * CPT + j];
    }
    float s1 = 0.f, s2 = 0.f;
    #pragma unroll
    for (int j = 0; j < CPT; ++j) {
        s1 += acc[j] * a_s[q * C + j];
        s2 += acc[j] * a_d[q * C + j];
    }
    SS[(unsigned)n * H + q] = s1;
    SD[(unsigned)n * H + q] = s2;
    #pragma unroll
    for (int j = 0; j < CPT; j += 2)
        *(__half2*)&Hh[(size_t)n * COUT + q * CPT + j] = __floats2half2_rn(acc[j], acc[j + 1]);
}

// ---------------- mean-pool: grid (NG,3), block 128 = 8 rows x 16 lanes x 2ch (half2) ----------------

__global__ __launch_bounds__(128) void pool_kernel(const __half* __restrict__ GO,
                                                   const float* __restrict__ scale,
                                                   const float* __restrict__ shift,
                                                   const int* __restrict__ goff,
                                                   float* __restrict__ pooled) {
    __shared__ float red[8][16][2];
    int g = blockIdx.x;
    int lp = threadIdx.x & 15;
    int row = threadIdx.x >> 4;
    int ch = blockIdx.y * 32 + lp * 2;
    int beg = goff[g], end = goff[g + 1];
    float sc0 = scale[ch], sh0 = shift[ch];
    float sc1 = scale[ch + 1], sh1 = shift[ch + 1];
    float s0 = 0.f, s1 = 0.f;
    for (int n = beg + row; n < end; n += 8) {
        float2 v = __half22float2(*(const __half2*)&GO[(size_t)n * 96 + ch]);
        s0 += fmaxf(v.x * sc0 + sh0, 0.f);
        s1 += fmaxf(v.y * sc1 + sh1, 0.f);
    }
    red[row][lp][0] = s0;
    red[row][lp][1] = s1;
    __syncthreads();
    if (row == 0) {
        #pragma unroll
        for (int r = 1; r < 8; ++r) { s0 += red[r][lp][0]; s1 += red[r][lp][1]; }
        float cnt = fmaxf((float)(end - beg), 1.f);
        pooled[g * 96 + ch] = s0 / cnt;
        pooled[g * 96 + ch + 1] = s1 / cnt;
    }
}

__global__ void final_gemm(const float* __restrict__ pooled, const float* __restrict__ oW,
                           const float* __restrict__ ob, float* __restrict__ out) {
    int idx = blockIdx.x * blockDim.x + threadIdx.x;
    if (idx >= NG * 10) return;
    int g = idx / 10, k = idx % 10;
    float s = ob[k];
    for (int c = 0; c < 96; ++c) s += pooled[g * 96 + c] * oW[c * 10 + k];
    out[idx] = s;
}

// ---------------- launch ----------------

extern "C" void kernel_launch(void* const* d_in, const int* in_sizes, int n_in,
                              void* d_out, int out_size, void* d_ws, size_t ws_size,
                              hipStream_t stream) {
    const float* x   = (const float*)d_in[0];
    const int*   ei  = (const int*)d_in[1];
    const int*   bat = (const int*)d_in[2];
    const float *W1 = (const float*)d_in[3], *a1s = (const float*)d_in[4],
                *a1d = (const float*)d_in[5], *b1 = (const float*)d_in[6],
                *g1 = (const float*)d_in[7], *be1 = (const float*)d_in[8],
                *lW1 = (const float*)d_in[9], *lb1 = (const float*)d_in[10],
                *gl1 = (const float*)d_in[11], *bel1 = (const float*)d_in[12],
                *W2 = (const float*)d_in[13], *a2s = (const float*)d_in[14],
                *a2d = (const float*)d_in[15], *b2 = (const float*)d_in[16],
                *g2 = (const float*)d_in[17], *be2 = (const float*)d_in[18],
                *lW2 = (const float*)d_in[19], *lb2 = (const float*)d_in[20],
                *gl2 = (const float*)d_in[21], *bel2 = (const float*)d_in[22],
                *W3 = (const float*)d_in[23], *a3s = (const float*)d_in[24],
                *a3d = (const float*)d_in[25], *b3 = (const float*)d_in[26],
                *g3 = (const float*)d_in[27], *be3 = (const float*)d_in[28],
                *oW = (const float*)d_in[29], *ob = (const float*)d_in[30];
    float* out = (float*)d_out;

    // workspace layout
    int* iw      = (int*)d_ws;
    int* bcur    = iw;                   // NB  (memset)
    int* counts  = bcur + NB;            // NN
    int* offsets = counts + NN;          // NN+1 (padded offsets)
    int* goff    = offsets + NN + 1;     // NG+1
    int* bsum    = goff + NG + 1;        // SCAN_NB
    int* boff    = bsum + SCAN_NB;       // SCAN_NB+1
    int* srcs    = boff + SCAN_NB + 1;   // PSLOTS (includes +16 overrun pad)
    float* fw      = (float*)(srcs + PSLOTS);
    __half* GOh    = (__half*)fw;                // NN*96 halves (region reserved NN*96 floats)
    float* Ub      = fw + (size_t)NN * 96;       // NN*16
    float* SSb     = Ub + (size_t)NN * 16;       // NN*8
    float* SDb     = SSb + (size_t)NN * 8;       // NN*8
    float* partial = SDb + (size_t)NN * 8;       // STATS_BLOCKS*192
    float* scaleA  = partial + STATS_BLOCKS * 192;
    float* shiftA  = scaleA + 96;
    float* scaleB  = shiftA + 96;
    float* shiftB  = scaleB + 16;
    float* pooled  = shiftB + 16;                // NG*96
    __half* Hh     = (__half*)(pooled + NG * 96);     // NN*96 halves
    unsigned* pairs = (unsigned*)GOh;            // aliases GO region during preprocessing

    const float invN = 1.0f / (float)NN;

    // ---- edge bucket sort -> padded CSR (shared by all layers) ----
    hipMemsetAsync(bcur, 0, NB * sizeof(int), stream);
    hipMemsetAsync(srcs, 0, (size_t)PSLOTS * sizeof(int), stream);
    part_pass1<<<(ET + CHUNK - 1) / CHUNK, 256, 0, stream>>>(ei, bcur, pairs);
    graph_bounds<<<3, 256, 0, stream>>>(bat, goff);
    bucket_counts<<<NB, 256, 0, stream>>>(pairs, bcur, counts);
    scan_reduce<<<SCAN_NB, 256, 0, stream>>>(counts, bsum);
    scan_bsums<<<1, 128, 0, stream>>>(bsum, SCAN_NB, boff, &offsets[NN]);
    scan_final<<<SCAN_NB, SCAN_B, 0, stream>>>(counts, boff, offsets);
    bucket_scatter<<<NB, 256, 0, stream>>>(pairs, bcur, offsets, srcs);

    // ---- layer 1 ----
    gemm1<<<(NN + 31) / 32, 256, 0, stream>>>(x, W1, a1s, a1d, Hh, SSb, SDb);
    gat_kernel<8, 8, 1, 8><<<(NN + 3) / 4, 256, 0, stream>>>(Hh, SSb, SDb, offsets, counts, srcs, b1, GOh);
    stats_h_kernel<<<STATS_BLOCKS, 256, 4 * 256 * sizeof(float), stream>>>(GOh, NN, 64, partial);
    bn_finalize<<<1, 512, 2 * 512 * sizeof(float), stream>>>(partial, STATS_BLOCKS, 64, invN, g1, be1, scaleA, shiftA);
    bnrelu_linear<8><<<(NN + 63) / 64, 256, 0, stream>>>(GOh, scaleA, shiftA, lW1, lb1, Ub);
    stats_kernel<<<STATS_BLOCKS, 256, 2 * 256 * sizeof(float), stream>>>(Ub, NN, 8, partial);
    bn_finalize<<<1, 512, 2 * 512 * sizeof(float), stream>>>(partial, STATS_BLOCKS, 8, invN, gl1, bel1, scaleB, shiftB);

    // ---- layer 2 ----
    bnrelu_gemm<8, 64, 4, 16><<<(NN + 63) / 64, 256, 0, stream>>>(Ub, scaleB, shiftB, W2, a2s, a2d, Hh, SSb, SDb);
    gat_kernel<4, 16, 1, 16><<<(NN + 3) / 4, 256, 0, stream>>>(Hh, SSb, SDb, offsets, counts, srcs, b2, GOh);
    stats_h_kernel<<<STATS_BLOCKS, 256, 4 * 256 * sizeof(float), stream>>>(GOh, NN, 64, partial);
    bn_finalize<<<1, 512, 2 * 512 * sizeof(float), stream>>>(partial, STATS_BLOCKS, 64, invN, g2, be2, scaleA, shiftA);
    bnrelu_linear<16><<<(NN + 63) / 64, 256, 0, stream>>>(GOh, scaleA, shiftA, lW2, lb2, Ub);
    stats_kernel<<<STATS_BLOCKS, 256, 2 * 256 * sizeof(float), stream>>>(Ub, NN, 16, partial);
    bn_finalize<<<1, 512, 2 * 512 * sizeof(float), stream>>>(partial, STATS_BLOCKS, 16, invN, gl2, bel2, scaleB, shiftB);

    // ---- layer 3 ----
    bnrelu_gemm<16, 96, 4, 24><<<(NN + 63) / 64, 256, 0, stream>>>(Ub, scaleB, shiftB, W3, a3s, a3d, Hh, SSb, SDb);
    gat_kernel<4, 24, 2, 8><<<(NN + 3) / 4, 256, 0, stream>>>(Hh, SSb, SDb, offsets, counts, srcs, b3, GOh);
    stats_h_kernel<<<STATS_BLOCKS, 192, 4 * 192 * sizeof(float), stream>>>(GOh, NN, 96, partial);
    bn_finalize<<<1, 768, 2 * 768 * sizeof(float), stream>>>(partial, STATS_BLOCKS, 96, invN, g3, be3, scaleA, shiftA);

    // ---- pool + head ----
    pool_kernel<<<dim3(NG, 3), 128, 0, stream>>>(GOh, scaleA, shiftA, goff, pooled);
    final_gemm<<<(NG * 10 + 255) / 256, 256, 0, stream>>>(pooled, oW, ob, out);
}